// Round 5
// baseline (165.562 us; speedup 1.0000x reference)
//
#include <hip/hip_runtime.h>

#define N_WORDS   16384
#define L_CHARS   16
#define CHAR_SIZE 128
#define C_EMB     64
#define CONV_L    256
#define KERNEL_K  3
#define D_EMB     300
#define OUT_STRIDE (CONV_L + D_EMB)   // 556
#define CH_Q      64                  // channels per quarter-slice
#define T_ROWQ    (KERNEL_K * CH_Q)   // 192 halves per (c) per quarter
#define SLICE_H   (CHAR_SIZE * T_ROWQ)  // 24576 halves = 48 KB

typedef _Float16 half8 __attribute__((ext_vector_type(8)));

static __device__ __forceinline__ half8 h8max(half8 a, half8 b) {
#if __has_builtin(__builtin_elementwise_max)
    return __builtin_elementwise_max(a, b);
#else
    half8 r;
    #pragma unroll
    for (int i = 0; i < 8; ++i) r[i] = a[i] > b[i] ? a[i] : b[i];
    return r;
#endif
}

// ---------------------------------------------------------------------------
// Merged build kernel: one block per char c. Four 48 KB chunks of w (64 o
// values each) are staged into LDS with coalesced global reads (R3 lesson:
// never read w strided from global). LDS layout wl[o_loc*193 + r] — the +1
// pad makes both the linear staging writes and the stride-193 compute reads
// conflict-free (bank = (ol + 3i + k) % 32 spans all banks).
//   Th[q][c][k][oi] = (half) sum_i emb[c][i] * w[o][i][k],  q=o>>6, oi=o&63
__global__ __launch_bounds__(256)
void build_table(const float* __restrict__ emb,
                 const float* __restrict__ w,
                 _Float16* __restrict__ Th) {
    __shared__ float wl[64 * 193];          // 49408 B
    const int c  = blockIdx.x;
    const int t  = threadIdx.x;
    const int kk = t >> 6;                  // 0..3 (3 = idle in compute)
    const int ol = t & 63;

    #pragma unroll
    for (int chunk = 0; chunk < 4; ++chunk) {
        __syncthreads();                    // protect wl from previous chunk
        // stage 64 o-rows (12288 floats), fully coalesced global reads
        #pragma unroll
        for (int j = 0; j < 48; ++j) {
            int idx   = t + j * 256;        // 0..12287
            int o_loc = idx / 192;
            int r     = idx - o_loc * 192;  // i*3 + k
            wl[o_loc * 193 + r] = w[(size_t)(chunk * 64 + o_loc) * 192 + r];
        }
        __syncthreads();
        if (kk < 3) {
            float s = 0.f;
            #pragma unroll
            for (int i = 0; i < C_EMB; ++i)
                s += emb[c * C_EMB + i] * wl[ol * 193 + i * 3 + kk];
            // q == chunk, oi == ol
            Th[chunk * SLICE_H + c * T_ROWQ + kk * CH_Q + ol] = (_Float16)s;
        }
    }
}

// ---------------------------------------------------------------------------
// Main kernel: 768 blocks, exactly 3/CU resident (48 KB LDS), no second
// scheduling round. q = blockIdx&3 so a block's char jobs (b and b+768)
// share one LDS slice -> staged once. Blocks 0..255: two char jobs.
// Blocks 256..767: one char job + 32-word embedding gather (balances).
// Char inner loop: wave = 8 words (8-lane groups), lane owns 8 channels,
// half8 ds_reads, packed-fp16 sliding 3-deep conv accumulator (R4-proven).
__global__ __launch_bounds__(256, 3)
void main_kernel(const int* __restrict__ X,
                 const int* __restrict__ Xw,
                 const _Float16* __restrict__ Th,
                 const float* __restrict__ conv_b,
                 const float* __restrict__ word_emb,
                 float* __restrict__ out) {
    __shared__ __align__(16) _Float16 Ts[SLICE_H];   // 48 KB

    const int b    = blockIdx.x;         // 0..767
    const int t    = threadIdx.x;
    const int lane = t & 63;
    const int wv   = t >> 6;
    const int q    = b & 3;

    // ---- stage the 48 KB slice once (contiguous, coalesced) ----
    {
        const float4* src = (const float4*)(Th + q * SLICE_H);
        float4* dst = (float4*)Ts;
        #pragma unroll
        for (int i = 0; i < 12; ++i)
            dst[t + i * 256] = src[t + i * 256];
    }
    __syncthreads();

    const int g  = lane >> 3;   // word within the wave's 8
    const int l8 = lane & 7;    // owns channels q*64 + l8*8 .. +8

    float bias[8];
    {
        const float4* bp = (const float4*)(conv_b + q * CH_Q + l8 * 8);
        float4 b0 = bp[0], b1 = bp[1];
        bias[0]=b0.x; bias[1]=b0.y; bias[2]=b0.z; bias[3]=b0.w;
        bias[4]=b1.x; bias[5]=b1.y; bias[6]=b1.z; bias[7]=b1.w;
    }

    for (int job = b; job < 1024; job += 768) {
        const int wgrp = job >> 2;        // 0..255, q = job&3 == b&3
        #pragma unroll
        for (int pass = 0; pass < 2; ++pass) {
            const int n = wgrp * 64 + pass * 32 + wv * 8 + g;

            const int4* xr = (const int4*)(X + n * L_CHARS);
            int4 q0 = xr[0], q1 = xr[1], q2 = xr[2], q3 = xr[3];
            int cs[16] = {q0.x, q0.y, q0.z, q0.w,
                          q1.x, q1.y, q1.z, q1.w,
                          q2.x, q2.y, q2.z, q2.w,
                          q3.x, q3.y, q3.z, q3.w};

            half8 a0 = (half8)(_Float16)0.f;
            half8 a1 = (half8)(_Float16)0.f;
            half8 m  = (half8)(_Float16)(-65504.f);

            #pragma unroll
            for (int j = 0; j < L_CHARS; ++j) {
                const _Float16* row = Ts + cs[j] * T_ROWQ + l8 * 8;
                half8 t0 = *(const half8*)(row);             // k=0
                half8 t1 = *(const half8*)(row + CH_Q);      // k=1
                half8 t2 = *(const half8*)(row + 2 * CH_Q);  // k=2
                half8 yj = a0 + t2;          // y[j] complete
                m  = h8max(m, yj);
                a0 = a1 + t1;                // partial y[j+1]
                a1 = t0;                     // partial y[j+2]
            }
            m = h8max(m, a0);   // y[16]
            m = h8max(m, a1);   // y[17]

            float r[8];
            #pragma unroll
            for (int e = 0; e < 8; ++e)
                r[e] = fmaxf((float)m[e] + bias[e], 0.f);
            float4* dst = (float4*)(out + (size_t)n * OUT_STRIDE + q * CH_Q + l8 * 8);
            dst[0] = make_float4(r[0], r[1], r[2], r[3]);
            dst[1] = make_float4(r[4], r[5], r[6], r[7]);
        }
    }

    // ---- word-embedding gather on the single-char-job blocks ----
    if (b >= 256) {
        const int wb = b - 256;                 // 0..511, 32 words each
        #pragma unroll
        for (int s = 0; s < 8; ++s) {
            int n = wb * 32 + wv * 8 + s;
            int widx = Xw[n];
            const float4* src = (const float4*)(word_emb + (size_t)widx * D_EMB);
            float4* dst = (float4*)(out + (size_t)n * OUT_STRIDE + CONV_L);
            dst[lane] = src[lane];
            if (lane < (D_EMB / 4 - 64)) {      // remaining 11 float4
                dst[64 + lane] = src[64 + lane];
            }
        }
    }
}

extern "C" void kernel_launch(void* const* d_in, const int* in_sizes, int n_in,
                              void* d_out, int out_size, void* d_ws, size_t ws_size,
                              hipStream_t stream) {
    const int*   X    = (const int*)d_in[0];
    const int*   Xw   = (const int*)d_in[1];
    const float* emb  = (const float*)d_in[2];
    const float* w    = (const float*)d_in[3];
    const float* b    = (const float*)d_in[4];
    const float* we   = (const float*)d_in[5];
    float* out = (float*)d_out;

    _Float16* Th = (_Float16*)d_ws;   // 4*24576*2 = 196608 B of workspace

    build_table<<<CHAR_SIZE, 256, 0, stream>>>(emb, w, Th);
    main_kernel<<<768, 256, 0, stream>>>(X, Xw, Th, b, we, out);
}

// Round 7
// 135.370 us; speedup vs baseline: 1.2230x; 1.2230x over previous
//
#include <hip/hip_runtime.h>

#define N_WORDS   16384
#define L_CHARS   16
#define CHAR_SIZE 128
#define C_EMB     64
#define CONV_L    256
#define KERNEL_K  3
#define D_EMB     300
#define OUT_STRIDE (CONV_L + D_EMB)   // 556
#define CH_Q      64                  // channels per quarter-slice
#define SLICE_H   (CHAR_SIZE * KERNEL_K * CH_Q)   // 24576 halves = 48 KB

typedef _Float16 half8 __attribute__((ext_vector_type(8)));

static __device__ __forceinline__ half8 h8max(half8 a, half8 b) {
#if __has_builtin(__builtin_elementwise_max)
    return __builtin_elementwise_max(a, b);
#else
    half8 r;
    #pragma unroll
    for (int i = 0; i < 8; ++i) r[i] = a[i] > b[i] ? a[i] : b[i];
    return r;
#endif
}

// ---------------------------------------------------------------------------
// Kernel A (R2-proven): transpose conv_w (O,I,K) -> Wt (I,K,O). Coalesced
// reads; scattered writes (fine, 196 KB).
__global__ void transpose_w(const float* __restrict__ w, float* __restrict__ Wt) {
    int tid = blockIdx.x * blockDim.x + threadIdx.x;
    if (tid >= CONV_L * C_EMB * KERNEL_K) return;
    int o = tid / (C_EMB * KERNEL_K);
    int r = tid - o * (C_EMB * KERNEL_K);
    int i = r / KERNEL_K;
    int k = r - i * KERNEL_K;
    Wt[i * (KERNEL_K * CONV_L) + k * CONV_L + o] = w[tid];
}

// ---------------------------------------------------------------------------
// Kernel B: folded table, written in quarter-sliced layout:
//   Th[q][c][k][oi] = (half) sum_i emb[c][i] * Wt[i][k][q*64+oi]
// Block (c,k); thread o. Wt reads coalesced (1 KB/wave/iter, L2-resident).
__global__ void build_table(const float* __restrict__ emb,
                            const float* __restrict__ Wt,
                            _Float16* __restrict__ Th) {
    int c = blockIdx.x / 3;
    int k = blockIdx.x % 3;
    int o = threadIdx.x;
    const float* erow = emb + c * C_EMB;
    float s = 0.f;
    #pragma unroll
    for (int i = 0; i < C_EMB; ++i)
        s += erow[i] * Wt[i * (KERNEL_K * CONV_L) + k * CONV_L + o];
    int q  = o >> 6;
    int oi = o & 63;
    Th[q * SLICE_H + c * (KERNEL_K * CH_Q) + k * CH_Q + oi] = (_Float16)s;
}

// ---------------------------------------------------------------------------
// Kernel C (fused main).
// Blocks [0, WB): word-embedding gather (no LDS use).
// Blocks [WB, WB+CB): char conv/maxpool with the table slice staged in LDS.
//   CB = 1024 char blocks: q = cb&3 (channel quarter), wgrp = cb>>2 selects
//   64 words. Each block stages its contiguous 48 KB slice once (coalesced),
//   then 4 waves x 8-lane groups process 8 words/wave/pass, 2 passes.
//   Lane owns 8 channels -> half8 (16 B) ds_read per (char,k); uniform bank
//   coverage (each group's 8x16B spans all 32 banks).
__global__ __launch_bounds__(256, 3)
void main_kernel(const int* __restrict__ X,
                 const int* __restrict__ Xw,
                 const _Float16* __restrict__ Th,
                 const float* __restrict__ conv_b,
                 const float* __restrict__ word_emb,
                 float* __restrict__ out,
                 int word_blocks) {
    __shared__ __align__(16) _Float16 Ts[SLICE_H];   // 48 KB

    const int lane = threadIdx.x & 63;
    const int wv   = threadIdx.x >> 6;

    if ((int)blockIdx.x < word_blocks) {
        const int wavesTotal = word_blocks * 4;
        const int waveId = blockIdx.x * 4 + wv;
        for (int n = waveId; n < N_WORDS; n += wavesTotal) {
            int widx = Xw[n];
            const float4* src = (const float4*)(word_emb + (size_t)widx * D_EMB);
            float4* dst = (float4*)(out + (size_t)n * OUT_STRIDE + CONV_L);
            dst[lane] = src[lane];
            if (lane < (D_EMB / 4 - 64)) {
                dst[64 + lane] = src[64 + lane];
            }
        }
        return;
    }

    const int cb   = (int)blockIdx.x - word_blocks;   // 0..1023
    const int q    = cb & 3;                          // channel quarter
    const int wgrp = cb >> 2;                         // word group, 0..255

    // ---- stage the 48 KB slice (fully coalesced contiguous read) ----
    {
        const float4* src = (const float4*)(Th + q * SLICE_H);
        float4* dst = (float4*)Ts;
        #pragma unroll
        for (int i = 0; i < 12; ++i)
            dst[threadIdx.x + i * 256] = src[threadIdx.x + i * 256];
    }
    __syncthreads();

    const int g  = lane >> 3;   // word within the wave's 8
    const int l8 = lane & 7;    // owns channels q*64 + l8*8 .. +8

    float bias[8];
    {
        const float4* bp = (const float4*)(conv_b + q * CH_Q + l8 * 8);
        float4 b0 = bp[0], b1 = bp[1];
        bias[0]=b0.x; bias[1]=b0.y; bias[2]=b0.z; bias[3]=b0.w;
        bias[4]=b1.x; bias[5]=b1.y; bias[6]=b1.z; bias[7]=b1.w;
    }

    #pragma unroll
    for (int pass = 0; pass < 2; ++pass) {
        const int n = wgrp * 64 + pass * 32 + wv * 8 + g;

        // all 8 lanes of the group load the word's 16 chars (same 64 B row;
        // L1 broadcast)
        const int4* xr = (const int4*)(X + n * L_CHARS);
        int4 q0 = xr[0], q1 = xr[1], q2 = xr[2], q3 = xr[3];
        int cs[16] = {q0.x, q0.y, q0.z, q0.w,
                      q1.x, q1.y, q1.z, q1.w,
                      q2.x, q2.y, q2.z, q2.w,
                      q3.x, q3.y, q3.z, q3.w};

        half8 a0 = (half8)(_Float16)0.f;
        half8 a1 = (half8)(_Float16)0.f;
        half8 m  = (half8)(_Float16)(-65504.f);

        #pragma unroll
        for (int j = 0; j < L_CHARS; ++j) {
            const _Float16* row = Ts + cs[j] * (KERNEL_K * CH_Q) + l8 * 8;
            half8 t0 = *(const half8*)(row);            // k=0
            half8 t1 = *(const half8*)(row + CH_Q);     // k=1
            half8 t2 = *(const half8*)(row + 2*CH_Q);   // k=2
            half8 yj = a0 + t2;          // y[j] complete
            m  = h8max(m, yj);
            a0 = a1 + t1;                // partial y[j+1]
            a1 = t0;                     // partial y[j+2]
        }
        m = h8max(m, a0);   // y[16]
        m = h8max(m, a1);   // y[17]

        float r[8];
        #pragma unroll
        for (int e = 0; e < 8; ++e)
            r[e] = fmaxf((float)m[e] + bias[e], 0.f);
        float4* dst = (float4*)(out + (size_t)n * OUT_STRIDE + q * CH_Q + l8 * 8);
        dst[0] = make_float4(r[0], r[1], r[2], r[3]);
        dst[1] = make_float4(r[4], r[5], r[6], r[7]);
    }
}

extern "C" void kernel_launch(void* const* d_in, const int* in_sizes, int n_in,
                              void* d_out, int out_size, void* d_ws, size_t ws_size,
                              hipStream_t stream) {
    const int*   X    = (const int*)d_in[0];
    const int*   Xw   = (const int*)d_in[1];
    const float* emb  = (const float*)d_in[2];
    const float* w    = (const float*)d_in[3];
    const float* b    = (const float*)d_in[4];
    const float* we   = (const float*)d_in[5];
    float* out = (float*)d_out;

    // ws layout: Th (fp16, 196608 B) | Wt (fp32, 196608 B)
    _Float16* Th = (_Float16*)d_ws;
    float*    Wt = (float*)((char*)d_ws + 4 * SLICE_H * sizeof(_Float16));

    transpose_w<<<(CONV_L * C_EMB * KERNEL_K + 255) / 256, 256, 0, stream>>>(w, Wt);
    build_table<<<CHAR_SIZE * KERNEL_K, 256, 0, stream>>>(emb, Wt, Th);

    const int WB = 256;    // word-gather blocks
    const int CB = 1024;   // char blocks: 4 quarters x 256 word-groups
    main_kernel<<<WB + CB, 256, 0, stream>>>(X, Xw, Th, b, we, out, WB);
}